// Round 17
// baseline (55.297 us; speedup 1.0000x reference)
//
#include <hip/hip_runtime.h>
#include <stdint.h>

#define H 128
#define W 128
#define CIN 64
#define COUT 64
#define NB 8
#define WR 8        // pixel rows per block (2 row-quads)
#define WC 16       // pixel cols per block
#define CW 20       // staged cols per window row (WC+4)
#define NR 12       // staged rows (WR+4)
#define PLANE 242   // slots per chunk-plane; 242 % 8 == 2 -> quarter decorrelation

typedef __attribute__((ext_vector_type(4))) float f32x4;
typedef __attribute__((ext_vector_type(2))) _Float16 f16x2;
typedef __attribute__((ext_vector_type(8))) _Float16 f16x8;
typedef __attribute__((ext_vector_type(4))) unsigned int u32x4;
typedef __attribute__((ext_vector_type(2))) unsigned int u32x2;

__device__ __forceinline__ f16x2 bch2(unsigned u) { return __builtin_bit_cast(f16x2, u); }
__device__ __forceinline__ unsigned bcu(f16x2 v) { return __builtin_bit_cast(unsigned, v); }

// ---- kernel 0: x NCHW f32 -> NHWC f16 (xt[b][h][w][c]) via LDS tile transpose
__global__ __launch_bounds__(256) void x_to_nhwc(const float* __restrict__ x,
                                                 _Float16* __restrict__ xt) {
    __shared__ _Float16 tile[W][68];
    int bh = blockIdx.x;
    int h = bh & (H - 1), b = bh >> 7;
    int t = threadIdx.x;
    #pragma unroll
    for (int i = 0; i < 8; ++i) {
        int idx = i * 256 + t;
        int c = idx >> 5;
        int w4 = (idx & 31) << 2;
        f32x4 v = *(const f32x4*)(x + (((size_t)(b * CIN + c) * H + h) * W + w4));
        #pragma unroll
        for (int j = 0; j < 4; ++j) tile[w4 + j][c] = (_Float16)v[j];
    }
    __syncthreads();
    _Float16* dst = xt + (size_t)bh * W * CIN;
    #pragma unroll
    for (int i = 0; i < 8; ++i) {
        int idx = i * 256 + t;
        int w = idx >> 4;
        int c4 = (idx & 15) << 2;
        *(uint2*)(dst + (size_t)w * CIN + c4) = *(const uint2*)&tile[w][c4];
    }
}

// ---- kernel 1: prepack weights, MFMA-lane-coalesced layout
__global__ __launch_bounds__(256) void prep_w(const float* __restrict__ wo,
                                              const float* __restrict__ wc,
                                              _Float16* __restrict__ wao2,
                                              _Float16* __restrict__ wac2) {
    int t = blockIdx.x * 256 + threadIdx.x;
    if (t < 18432) {
        int j = t & 7, l = (t >> 3) & 63, m = (t >> 9) & 1, kk = t >> 10;
        int cout = m * 16 + (l & 15);
        int cin = (kk & 1) * 32 + ((l >> 4) << 3) + j;
        wao2[t] = (cout < 18) ? (_Float16)wo[(cout * 64 + cin) * 9 + (kk >> 1)]
                              : (_Float16)0.f;
    } else if (t < 18432 + 36864) {
        int u = t - 18432;
        int j = u & 7, l = (u >> 3) & 63, m = (u >> 9) & 3, kk = u >> 11;
        int cout = m * 16 + (l & 15);
        int cin = (kk & 1) * 32 + ((l >> 4) << 3) + j;
        wac2[u] = (_Float16)wc[(cout * 64 + cin) * 9 + (kk >> 1)];
    }
}

// ---- kernel 2: fused offset-conv + coord setup + deformable conv.
// 256 thr = 4 waves: half = wv>>1 (K-split), q = wv&1 (row-quad).
// Each wave owns FOUR rows -> 4 independent dependency chains per tap.
// Unified smem: s_x planes + meta; merged single-round epilogue reuses both.
__global__ __launch_bounds__(256, 3) void deform_fused(const _Float16* __restrict__ xt,
                                                       const _Float16* __restrict__ wao2,
                                                       const _Float16* __restrict__ wac2,
                                                       const float* __restrict__ bo,
                                                       const float* __restrict__ bconv,
                                                       float* __restrict__ out) {
    __shared__ __align__(16) char smem[44800];      // 30976 s_x + 13824 meta
    u32x4* s_x   = (u32x4*)smem;                    // [8 planes][242 slots]
    float* s_metaF = (float*)(smem + 30976);        // [8 rows][432 floats]

    int bid = blockIdx.x;
    int b = bid & 7;                      // XCD swizzle: XCD k <- batch k
    int r = bid >> 3;                     // 0..127
    int h0 = ((r >> 3) & 15) << 3;
    int w0 = (r & 7) << 4;
    int vy = h0 - 2, vx = w0 - 2;         // window origin (12 rows x 20 cols)

    int t = threadIdx.x;
    int lane = t & 63, wv = t >> 6;
    int q = wv & 1;                       // row-quad index
    int half = wv >> 1;                   // 0: ch 0..31, 1: ch 32..63
    int pcol = lane & 15, hq = lane >> 4;
    int pl = half * 4 + hq;               // this lane's channel chunk (8 ch)
    int rbase = h0 + 4 * q;               // this wave's first row
    int wp = w0 + pcol;

    const _Float16* xb = xt + (size_t)b * H * W * CIN;

    // ---------- stage x window (clamp-uniform, all 256 threads) ----------
    for (int i = t; i < NR * CW * 8; i += 256) {
        int ch = i & 7;
        int q2 = i >> 3;
        int rr = q2 / CW;
        int cs = q2 - rr * CW;
        int row = min(max(vy + rr, 0), H - 1);
        int col = min(max(vx + cs, 0), W - 1);
        s_x[ch * PLANE + rr * CW + cs] =
            *(const u32x4*)(xb + (size_t)(row * W + col) * CIN + (ch << 3));
    }
    __syncthreads();                      // barrier 1

    const u32x4* sp = s_x + pl * PLANE;

    // ---------- phase A: offset conv via MFMA, 4 rows per wave ----------
    f32x4 aO0[4] = {}, aO1[4] = {};
    #pragma unroll
    for (int k = 0; k < 9; ++k) {
        int ky = k / 3 - 1, kx = k % 3 - 1;
        int xx = wp + kx;
        bool vx_ok = (unsigned)xx < (unsigned)W;
        int xc = min(max(xx, 0), W - 1) - vx;
        const _Float16* wb = wao2 + (size_t)(4 * k + 2 * half) * 512 + lane * 8;
        f16x8 a0 = *(const f16x8*)(wb);
        f16x8 a1 = *(const f16x8*)(wb + 512);
        #pragma unroll
        for (int rr = 0; rr < 4; ++rr) {
            int yy = rbase + rr + ky;
            int s = (min(max(yy, 0), H - 1) - vy) * CW + xc;
            u32x4 v = sp[s];
            u32x4 z = {};
            if (!(vx_ok && (unsigned)yy < (unsigned)H)) v = z;
            f16x8 bf = __builtin_bit_cast(f16x8, v);
            aO0[rr] = __builtin_amdgcn_mfma_f32_16x16x32_f16(a0, bf, aO0[rr], 0, 0, 0);
            aO1[rr] = __builtin_amdgcn_mfma_f32_16x16x32_f16(a1, bf, aO1[rr], 0, 0, 0);
        }
    }

    // ---------- reduce phase-A partials (half 1 -> LDS -> half 0) ----------
    if (half == 1) {
        #pragma unroll
        for (int rr = 0; rr < 4; ++rr) {
            float* sc = s_metaF + (4 * q + rr) * 432 + lane * 6;
            sc[0] = aO0[rr][0]; sc[1] = aO0[rr][1]; sc[2] = aO0[rr][2]; sc[3] = aO0[rr][3];
            sc[4] = aO1[rr][0]; sc[5] = aO1[rr][1];
        }
    }
    __syncthreads();                      // barrier 2

    if (half == 0) {
        // read partner partials FIRST (single-wave dataflow; writes follow reads)
        #pragma unroll
        for (int rr = 0; rr < 4; ++rr) {
            const float* sc = s_metaF + (4 * q + rr) * 432 + lane * 6;
            aO0[rr][0] += sc[0]; aO0[rr][1] += sc[1];
            aO0[rr][2] += sc[2]; aO0[rr][3] += sc[3];
            aO1[rr][0] += sc[4]; aO1[rr][1] += sc[5];
        }
        auto setup = [&](float* mrow, int row, int k, float dy, float dx) {
            float py = (float)(row + k / 3 - 1) + dy;
            float px = (float)(wp + k % 3 - 1) + dx;
            float y0f = floorf(py), x0f = floorf(px);
            float fy = py - y0f, fx = px - x0f;
            float vy0 = (y0f >= 0.f  && y0f <= 127.f) ? 1.f : 0.f;
            float vy1 = (y0f >= -1.f && y0f <= 126.f) ? 1.f : 0.f;
            float vx0 = (x0f >= 0.f  && x0f <= 127.f) ? 1.f : 0.f;
            float vx1 = (x0f >= -1.f && x0f <= 126.f) ? 1.f : 0.f;
            float g0 = (1.f - fy) * (1.f - fx) * vy0 * vx0;
            float g1 = (1.f - fy) * fx         * vy0 * vx1;
            float g2 = fy * (1.f - fx)         * vy1 * vx0;
            float g3 = fy * fx                 * vy1 * vx1;
            int y0i = (int)fminf(fmaxf(y0f, 0.f), 127.f);
            int x0i = (int)fminf(fmaxf(x0f, 0.f), 127.f);
            int y1i = (int)fminf(fmaxf(y0f + 1.f, 0.f), 127.f);
            int x1i = (int)fminf(fmaxf(x0f + 1.f, 0.f), 127.f);
            unsigned dxb = (unsigned)(x1i - x0i);
            unsigned dyb = (unsigned)(y1i - y0i);
            bool inw = (y0i >= vy) && (y1i <= vy + NR - 1) &&
                       (x0i >= vx) && (x1i <= vx + CW - 1);
            unsigned s00 = inw ? (unsigned)((y0i - vy) * CW + (x0i - vx)) : 0u;
            unsigned a00 = (unsigned)(y0i * W + x0i);
            unsigned awv = s00 | (dxb << 9) | (dyb << 10) | (inw ? 0u : (1u << 11)) | (a00 << 12);
            int idx = k * 16 + pcol;
            ((unsigned*)mrow)[idx] = awv;
            ((unsigned*)mrow)[144 + 2 * idx]     = bcu((f16x2){(_Float16)g0, (_Float16)g1});
            ((unsigned*)mrow)[144 + 2 * idx + 1] = bcu((f16x2){(_Float16)g2, (_Float16)g3});
        };
        f32x4 bo4 = *(const f32x4*)(bo + 4 * hq);
        #pragma unroll
        for (int rr = 0; rr < 4; ++rr) {
            float* mrow = s_metaF + (4 * q + rr) * 432;
            int row = rbase + rr;
            setup(mrow, row, 2 * hq,     aO0[rr][0] + bo4[0], aO0[rr][1] + bo4[1]);
            setup(mrow, row, 2 * hq + 1, aO0[rr][2] + bo4[2], aO0[rr][3] + bo4[3]);
            if (hq == 0) setup(mrow, row, 8, aO1[rr][0] + bo[16], aO1[rr][1] + bo[17]);
        }
    }
    __syncthreads();                      // barrier 3

    // ---------- phase C: deformable conv, 4 independent row-chains ----------
    const _Float16* xh = xb + (pl << 3);
    f32x4 acc[4][4] = {};                 // [rr][m]

    #pragma unroll
    for (int k = 0; k < 9; ++k) {
        const _Float16* ab = wac2 + (size_t)(8 * k + 4 * half) * 512 + lane * 8;
        f16x8 wm0 = *(const f16x8*)(ab);
        f16x8 wm1 = *(const f16x8*)(ab + 512);
        f16x8 wm2 = *(const f16x8*)(ab + 1024);
        f16x8 wm3 = *(const f16x8*)(ab + 1536);
        int idx = k * 16 + pcol;
        #pragma unroll
        for (int rr = 0; rr < 4; ++rr) {
            const unsigned* mrow = (const unsigned*)(s_metaF + (4 * q + rr) * 432);
            unsigned aw = mrow[idx];
            u32x2 wq = *(const u32x2*)&mrow[144 + 2 * idx];
            unsigned s0 = aw & 511u, dxb = (aw >> 9) & 1u, dyb = (aw >> 10) & 1u;
            u32x4 c00 = sp[s0], c01 = sp[s0 + dxb];
            u32x4 c10 = sp[s0 + dyb * CW], c11 = sp[s0 + dyb * CW + dxb];
            if (__builtin_expect((aw & (1u << 11)) != 0u, 0)) {
                unsigned a0_ = aw >> 12;
                c00 = *(const u32x4*)(xh + (size_t)a0_ * CIN);
                c01 = *(const u32x4*)(xh + (size_t)(a0_ + dxb) * CIN);
                c10 = *(const u32x4*)(xh + (size_t)(a0_ + (dyb << 7)) * CIN);
                c11 = *(const u32x4*)(xh + (size_t)(a0_ + (dyb << 7) + dxb) * CIN);
            }
            f16x2 wab = bch2(wq[0]), wcd = bch2(wq[1]);
            f16x2 w00d = (f16x2){wab[0], wab[0]}, w01d = (f16x2){wab[1], wab[1]};
            f16x2 w10d = (f16x2){wcd[0], wcd[0]}, w11d = (f16x2){wcd[1], wcd[1]};
            u32x4 fr;
            #pragma unroll
            for (int d = 0; d < 4; ++d) {
                f16x2 v = bch2(c00[d]) * w00d + bch2(c01[d]) * w01d
                        + bch2(c10[d]) * w10d + bch2(c11[d]) * w11d;
                fr[d] = bcu(v);
            }
            f16x8 bf = __builtin_bit_cast(f16x8, fr);
            acc[rr][0] = __builtin_amdgcn_mfma_f32_16x16x32_f16(wm0, bf, acc[rr][0], 0, 0, 0);
            acc[rr][1] = __builtin_amdgcn_mfma_f32_16x16x32_f16(wm1, bf, acc[rr][1], 0, 0, 0);
            acc[rr][2] = __builtin_amdgcn_mfma_f32_16x16x32_f16(wm2, bf, acc[rr][2], 0, 0, 0);
            acc[rr][3] = __builtin_amdgcn_mfma_f32_16x16x32_f16(wm3, bf, acc[rr][3], 0, 0, 0);
        }
    }

    // ---------- merged epilogue: ONE reduction round through unified smem ----
    __syncthreads();                      // barrier 4: smem fully dead
    float* red = (float*)smem;            // 8192 floats = 32.7 KB <= 44.8 KB
    if (half == 0) {
        #pragma unroll
        for (int rr = 0; rr < 4; ++rr)
            #pragma unroll
            for (int m = 0; m < 4; ++m)
                #pragma unroll
                for (int r2 = 0; r2 < 4; ++r2)
                    red[((m * 4 + r2) * 8 + q * 4 + rr) * 64 + lane] = acc[rr][m][r2];
    }
    __syncthreads();                      // barrier 5
    if (half == 1) {
        #pragma unroll
        for (int rr = 0; rr < 4; ++rr) {
            int row = rbase + rr;
            #pragma unroll
            for (int m = 0; m < 4; ++m) {
                f32x4 bc4 = *(const f32x4*)(bconv + m * 16 + (hq << 2));
                #pragma unroll
                for (int r2 = 0; r2 < 4; ++r2) {
                    int co = (m << 4) + (hq << 2) + r2;
                    float v = acc[rr][m][r2]
                            + red[((m * 4 + r2) * 8 + q * 4 + rr) * 64 + lane] + bc4[r2];
                    out[(((size_t)b * COUT + co) * H + row) * W + wp] = v;
                }
            }
        }
    }
}

extern "C" void kernel_launch(void* const* d_in, const int* in_sizes, int n_in,
                              void* d_out, int out_size, void* d_ws, size_t ws_size,
                              hipStream_t stream) {
    const float* x  = (const float*)d_in[0];
    const float* wo = (const float*)d_in[1];
    const float* bo = (const float*)d_in[2];
    const float* wc = (const float*)d_in[3];
    const float* bc = (const float*)d_in[4];
    float* out = (float*)d_out;

    _Float16* xt   = (_Float16*)d_ws;                                   // 16.78 MB
    _Float16* wao2 = (_Float16*)((char*)d_ws + (size_t)NB * H * W * CIN * 2);
    _Float16* wac2 = wao2 + 18432;

    x_to_nhwc<<<NB * H, 256, 0, stream>>>(x, xt);
    prep_w<<<(18432 + 36864 + 255) / 256, 256, 0, stream>>>(wo, wc, wao2, wac2);
    deform_fused<<<NB * H * W / (WR * WC), 256, 0, stream>>>(xt, wao2, wac2, bo, bc, out);
}

// Round 18
// 48.777 us; speedup vs baseline: 1.1337x; 1.1337x over previous
//
#include <hip/hip_runtime.h>
#include <stdint.h>

#define H 128
#define W 128
#define CIN 64
#define COUT 64
#define NB 8
#define WR 4        // pixel rows per block
#define WC 16       // pixel cols per block
#define CW 20       // staged cols per window row (WC+4)
#define NR 8        // staged rows (WR+4)
#define PLANE 162   // slots per chunk-plane; 162 % 8 == 2 -> quarter decorrelation
#define REDS 260    // reduction scratch row stride (floats)

typedef __attribute__((ext_vector_type(4))) float f32x4;
typedef __attribute__((ext_vector_type(2))) _Float16 f16x2;
typedef __attribute__((ext_vector_type(8))) _Float16 f16x8;
typedef __attribute__((ext_vector_type(4))) unsigned int u32x4;
typedef __attribute__((ext_vector_type(2))) unsigned int u32x2;

__device__ __forceinline__ f16x2 bch2(unsigned u) { return __builtin_bit_cast(f16x2, u); }
__device__ __forceinline__ unsigned bcu(f16x2 v) { return __builtin_bit_cast(unsigned, v); }

// ---- kernel 0 (fused): blocks 0..1023 = x NCHW f32 -> NHWC f16 transpose;
//      blocks 1024..  = weight prepack (MFMA-lane-coalesced layout).
__global__ __launch_bounds__(256) void prep_fused(const float* __restrict__ x,
                                                  _Float16* __restrict__ xt,
                                                  const float* __restrict__ wo,
                                                  const float* __restrict__ wc,
                                                  _Float16* __restrict__ wao2,
                                                  _Float16* __restrict__ wac2) {
    __shared__ _Float16 tile[W][68];
    int bid = blockIdx.x;
    int t = threadIdx.x;
    if (bid < NB * H) {
        int bh = bid;
        int h = bh & (H - 1), b = bh >> 7;
        #pragma unroll
        for (int i = 0; i < 8; ++i) {
            int idx = i * 256 + t;
            int c = idx >> 5;
            int w4 = (idx & 31) << 2;
            f32x4 v = *(const f32x4*)(x + (((size_t)(b * CIN + c) * H + h) * W + w4));
            #pragma unroll
            for (int j = 0; j < 4; ++j) tile[w4 + j][c] = (_Float16)v[j];
        }
        __syncthreads();
        _Float16* dst = xt + (size_t)bh * W * CIN;
        #pragma unroll
        for (int i = 0; i < 8; ++i) {
            int idx = i * 256 + t;
            int w = idx >> 4;
            int c4 = (idx & 15) << 2;
            *(uint2*)(dst + (size_t)w * CIN + c4) = *(const uint2*)&tile[w][c4];
        }
    } else {
        int u0 = (bid - NB * H) * 256 + t;
        if (u0 < 18432) {
            int j = u0 & 7, l = (u0 >> 3) & 63, m = (u0 >> 9) & 1, kk = u0 >> 10;
            int cout = m * 16 + (l & 15);
            int cin = (kk & 1) * 32 + ((l >> 4) << 3) + j;
            wao2[u0] = (cout < 18) ? (_Float16)wo[(cout * 64 + cin) * 9 + (kk >> 1)]
                                   : (_Float16)0.f;
        } else if (u0 < 18432 + 36864) {
            int u = u0 - 18432;
            int j = u & 7, l = (u >> 3) & 63, m = (u >> 9) & 3, kk = u >> 11;
            int cout = m * 16 + (l & 15);
            int cin = (kk & 1) * 32 + ((l >> 4) << 3) + j;
            wac2[u] = (_Float16)wc[(cout * 64 + cin) * 9 + (kk >> 1)];
        }
    }
}

// ---- kernel 1: fused offset-conv + coord setup + deformable conv.
// R16 exact (best measured: deform 41.4us): 256 thr = 4 waves, wv = half*2+q;
// K-split (half) x row-pair (q), 2 independent row-chains per wave.
__global__ __launch_bounds__(256, 4) void deform_fused(const _Float16* __restrict__ xt,
                                                       const _Float16* __restrict__ wao2,
                                                       const _Float16* __restrict__ wac2,
                                                       const float* __restrict__ bo,
                                                       const float* __restrict__ bconv,
                                                       float* __restrict__ out) {
    __shared__ u32x4 s_x[8 * PLANE];     // 20.7 KB chunk-planes
    __shared__ float s_meta[4][432];     // per pixel-row: aw[144] | wq pairs[288]

    int bid = blockIdx.x;
    int b = bid & 7;                      // XCD swizzle: XCD k <- batch k
    int r = bid >> 3;                     // 0..255
    int h0 = ((r >> 3) & 31) << 2;
    int w0 = (r & 7) << 4;
    int vy = h0 - 2, vx = w0 - 2;         // virtual window origin

    int t = threadIdx.x;
    int lane = t & 63, wv = t >> 6;
    int q = wv & 1;                       // row-pair index
    int half = wv >> 1;                   // 0: ch 0..31, 1: ch 32..63
    int pcol = lane & 15, hq = lane >> 4;
    int pl = half * 4 + hq;               // this lane's channel chunk (8 ch)
    int r0 = h0 + 2 * q, r1 = r0 + 1;
    int wp = w0 + pcol;

    const _Float16* xb = xt + (size_t)b * H * W * CIN;

    // ---------- stage x window (clamp-uniform, all 256 threads) ----------
    for (int i = t; i < NR * CW * 8; i += 256) {
        int ch = i & 7;
        int q2 = i >> 3;
        int rr = q2 / CW;
        int cs = q2 - rr * CW;
        int row = min(max(vy + rr, 0), H - 1);
        int col = min(max(vx + cs, 0), W - 1);
        s_x[ch * PLANE + rr * CW + cs] =
            *(const u32x4*)(xb + (size_t)(row * W + col) * CIN + (ch << 3));
    }
    __syncthreads();                      // barrier 1

    const u32x4* sp = s_x + pl * PLANE;

    // ---------- phase A: offset conv via MFMA, 2 rows per wave ----------
    f32x4 aA0 = {}, aA1 = {}, aB0 = {}, aB1 = {};
    #pragma unroll
    for (int k = 0; k < 9; ++k) {
        int ky = k / 3 - 1, kx = k % 3 - 1;
        int xx = wp + kx;
        bool vx_ok = (unsigned)xx < (unsigned)W;
        int xc = min(max(xx, 0), W - 1) - vx;
        int yyA = r0 + ky, yyB = r1 + ky;
        int sA = (min(max(yyA, 0), H - 1) - vy) * CW + xc;
        int sB = (min(max(yyB, 0), H - 1) - vy) * CW + xc;
        u32x4 vA = sp[sA], vB = sp[sB];
        u32x4 z = {};
        if (!(vx_ok && (unsigned)yyA < (unsigned)H)) vA = z;
        if (!(vx_ok && (unsigned)yyB < (unsigned)H)) vB = z;
        f16x8 bfA = __builtin_bit_cast(f16x8, vA);
        f16x8 bfB = __builtin_bit_cast(f16x8, vB);
        const _Float16* wb = wao2 + (size_t)(4 * k + 2 * half) * 512 + lane * 8;
        f16x8 a0 = *(const f16x8*)(wb);
        f16x8 a1 = *(const f16x8*)(wb + 512);
        aA0 = __builtin_amdgcn_mfma_f32_16x16x32_f16(a0, bfA, aA0, 0, 0, 0);
        aA1 = __builtin_amdgcn_mfma_f32_16x16x32_f16(a1, bfA, aA1, 0, 0, 0);
        aB0 = __builtin_amdgcn_mfma_f32_16x16x32_f16(a0, bfB, aB0, 0, 0, 0);
        aB1 = __builtin_amdgcn_mfma_f32_16x16x32_f16(a1, bfB, aB1, 0, 0, 0);
    }

    // ---------- reduce phase-A partials (half 1 -> LDS -> half 0) ----------
    if (half == 1) {
        float* scA = s_meta[2 * q] + lane * 6;
        scA[0] = aA0[0]; scA[1] = aA0[1]; scA[2] = aA0[2]; scA[3] = aA0[3];
        scA[4] = aA1[0]; scA[5] = aA1[1];
        float* scB = s_meta[2 * q + 1] + lane * 6;
        scB[0] = aB0[0]; scB[1] = aB0[1]; scB[2] = aB0[2]; scB[3] = aB0[3];
        scB[4] = aB1[0]; scB[5] = aB1[1];
    }
    __syncthreads();                      // barrier 2

    if (half == 0) {
        const float* scA = s_meta[2 * q] + lane * 6;
        const float* scB = s_meta[2 * q + 1] + lane * 6;
        float pA[6], pB[6];
        #pragma unroll
        for (int i = 0; i < 6; ++i) { pA[i] = scA[i]; pB[i] = scB[i]; }
        aA0[0] += pA[0]; aA0[1] += pA[1]; aA0[2] += pA[2]; aA0[3] += pA[3];
        aA1[0] += pA[4]; aA1[1] += pA[5];
        aB0[0] += pB[0]; aB0[1] += pB[1]; aB0[2] += pB[2]; aB0[3] += pB[3];
        aB1[0] += pB[4]; aB1[1] += pB[5];

        auto setup = [&](float* mrow, int row, int k, float dy, float dx) {
            float py = (float)(row + k / 3 - 1) + dy;
            float px = (float)(wp + k % 3 - 1) + dx;
            float y0f = floorf(py), x0f = floorf(px);
            float fy = py - y0f, fx = px - x0f;
            float vy0 = (y0f >= 0.f  && y0f <= 127.f) ? 1.f : 0.f;
            float vy1 = (y0f >= -1.f && y0f <= 126.f) ? 1.f : 0.f;
            float vx0 = (x0f >= 0.f  && x0f <= 127.f) ? 1.f : 0.f;
            float vx1 = (x0f >= -1.f && x0f <= 126.f) ? 1.f : 0.f;
            float g0 = (1.f - fy) * (1.f - fx) * vy0 * vx0;
            float g1 = (1.f - fy) * fx         * vy0 * vx1;
            float g2 = fy * (1.f - fx)         * vy1 * vx0;
            float g3 = fy * fx                 * vy1 * vx1;
            int y0i = (int)fminf(fmaxf(y0f, 0.f), 127.f);
            int x0i = (int)fminf(fmaxf(x0f, 0.f), 127.f);
            int y1i = (int)fminf(fmaxf(y0f + 1.f, 0.f), 127.f);
            int x1i = (int)fminf(fmaxf(x0f + 1.f, 0.f), 127.f);
            unsigned dxb = (unsigned)(x1i - x0i);
            unsigned dyb = (unsigned)(y1i - y0i);
            bool inw = (y0i >= vy) && (y1i <= vy + NR - 1) &&
                       (x0i >= vx) && (x1i <= vx + CW - 1);
            unsigned s00 = inw ? (unsigned)((y0i - vy) * CW + (x0i - vx)) : 0u;
            unsigned a00 = (unsigned)(y0i * W + x0i);
            unsigned awv = s00 | (dxb << 9) | (dyb << 10) | (inw ? 0u : (1u << 11)) | (a00 << 12);
            int idx = k * 16 + pcol;
            ((unsigned*)mrow)[idx] = awv;
            ((unsigned*)mrow)[144 + 2 * idx]     = bcu((f16x2){(_Float16)g0, (_Float16)g1});
            ((unsigned*)mrow)[144 + 2 * idx + 1] = bcu((f16x2){(_Float16)g2, (_Float16)g3});
        };
        f32x4 bo4 = *(const f32x4*)(bo + 4 * hq);
        setup(s_meta[2 * q],     r0, 2 * hq,     aA0[0] + bo4[0], aA0[1] + bo4[1]);
        setup(s_meta[2 * q],     r0, 2 * hq + 1, aA0[2] + bo4[2], aA0[3] + bo4[3]);
        setup(s_meta[2 * q + 1], r1, 2 * hq,     aB0[0] + bo4[0], aB0[1] + bo4[1]);
        setup(s_meta[2 * q + 1], r1, 2 * hq + 1, aB0[2] + bo4[2], aB0[3] + bo4[3]);
        if (hq == 0) {
            setup(s_meta[2 * q],     r0, 8, aA1[0] + bo[16], aA1[1] + bo[17]);
            setup(s_meta[2 * q + 1], r1, 8, aB1[0] + bo[16], aB1[1] + bo[17]);
        }
    }
    __syncthreads();                      // barrier 3

    // ---------- phase C: deformable conv, 2 independent row-chains ----------
    const _Float16* xh = xb + (pl << 3);
    const unsigned* mA = (const unsigned*)s_meta[2 * q];
    const unsigned* mB = (const unsigned*)s_meta[2 * q + 1];
    f32x4 accA[4] = {}, accB[4] = {};

    unsigned AWA[9], AWB[9];
    #pragma unroll
    for (int k = 0; k < 9; ++k) {
        AWA[k] = mA[k * 16 + pcol];
        AWB[k] = mB[k * 16 + pcol];
    }

    #pragma unroll
    for (int k = 0; k < 9; ++k) {
        int idx = k * 16 + pcol;
        unsigned awA = AWA[k];
        unsigned awB = AWB[k];
        u32x2 wqA = *(const u32x2*)&mA[144 + 2 * idx];
        u32x2 wqB = *(const u32x2*)&mB[144 + 2 * idx];
        unsigned sA = awA & 511u, dxA = (awA >> 9) & 1u, dyA = (awA >> 10) & 1u;
        unsigned sB = awB & 511u, dxB = (awB >> 9) & 1u, dyB = (awB >> 10) & 1u;
        u32x4 a00 = sp[sA], a01 = sp[sA + dxA];
        u32x4 a10 = sp[sA + dyA * CW], a11 = sp[sA + dyA * CW + dxA];
        u32x4 b00 = sp[sB], b01 = sp[sB + dxB];
        u32x4 b10 = sp[sB + dyB * CW], b11 = sp[sB + dyB * CW + dxB];
        if (__builtin_expect((awA & (1u << 11)) != 0u, 0)) {
            unsigned a0_ = awA >> 12;
            a00 = *(const u32x4*)(xh + (size_t)a0_ * CIN);
            a01 = *(const u32x4*)(xh + (size_t)(a0_ + dxA) * CIN);
            a10 = *(const u32x4*)(xh + (size_t)(a0_ + (dyA << 7)) * CIN);
            a11 = *(const u32x4*)(xh + (size_t)(a0_ + (dyA << 7) + dxA) * CIN);
        }
        if (__builtin_expect((awB & (1u << 11)) != 0u, 0)) {
            unsigned b0_ = awB >> 12;
            b00 = *(const u32x4*)(xh + (size_t)b0_ * CIN);
            b01 = *(const u32x4*)(xh + (size_t)(b0_ + dxB) * CIN);
            b10 = *(const u32x4*)(xh + (size_t)(b0_ + (dyB << 7)) * CIN);
            b11 = *(const u32x4*)(xh + (size_t)(b0_ + (dyB << 7) + dxB) * CIN);
        }
        f16x2 wa = bch2(wqA[0]), wc_ = bch2(wqA[1]);
        f16x2 A00 = (f16x2){wa[0], wa[0]},  A01 = (f16x2){wa[1], wa[1]};
        f16x2 A10 = (f16x2){wc_[0], wc_[0]}, A11 = (f16x2){wc_[1], wc_[1]};
        f16x2 wb_ = bch2(wqB[0]), wd_ = bch2(wqB[1]);
        f16x2 B00 = (f16x2){wb_[0], wb_[0]}, B01 = (f16x2){wb_[1], wb_[1]};
        f16x2 B10 = (f16x2){wd_[0], wd_[0]}, B11 = (f16x2){wd_[1], wd_[1]};
        u32x4 frA, frB;
        #pragma unroll
        for (int d = 0; d < 4; ++d) {
            f16x2 vA = bch2(a00[d]) * A00 + bch2(a01[d]) * A01
                     + bch2(a10[d]) * A10 + bch2(a11[d]) * A11;
            f16x2 vB = bch2(b00[d]) * B00 + bch2(b01[d]) * B01
                     + bch2(b10[d]) * B10 + bch2(b11[d]) * B11;
            frA[d] = bcu(vA);
            frB[d] = bcu(vB);
        }
        f16x8 bfA = __builtin_bit_cast(f16x8, frA);
        f16x8 bfB = __builtin_bit_cast(f16x8, frB);
        const _Float16* ab = wac2 + (size_t)(8 * k + 4 * half) * 512 + lane * 8;
        __builtin_amdgcn_s_setprio(1);
        #pragma unroll
        for (int m = 0; m < 4; ++m) {
            f16x8 wm = *(const f16x8*)(ab + m * 512);
            accA[m] = __builtin_amdgcn_mfma_f32_16x16x32_f16(wm, bfA, accA[m], 0, 0, 0);
            accB[m] = __builtin_amdgcn_mfma_f32_16x16x32_f16(wm, bfB, accB[m], 0, 0, 0);
        }
        __builtin_amdgcn_s_setprio(0);
    }

    // ---------- merged epilogue: ONE reduction round through s_x ----------
    __syncthreads();                      // barrier 4
    float* red = (float*)s_x;
    if (half == 0) {
        #pragma unroll
        for (int m = 0; m < 4; ++m)
            #pragma unroll
            for (int r2 = 0; r2 < 4; ++r2) {
                red[(m * 4 + r2) * REDS + q * 64 + lane]       = accA[m][r2];
                red[(m * 4 + r2) * REDS + 128 + q * 64 + lane] = accB[m][r2];
            }
    }
    __syncthreads();                      // barrier 5
    if (half == 1) {
        #pragma unroll
        for (int m = 0; m < 4; ++m) {
            f32x4 bc4 = *(const f32x4*)(bconv + m * 16 + (hq << 2));
            #pragma unroll
            for (int r2 = 0; r2 < 4; ++r2) {
                int co = (m << 4) + (hq << 2) + r2;
                float vA = accA[m][r2] + red[(m * 4 + r2) * REDS + q * 64 + lane] + bc4[r2];
                float vB = accB[m][r2] + red[(m * 4 + r2) * REDS + 128 + q * 64 + lane] + bc4[r2];
                out[(((size_t)b * COUT + co) * H + r0) * W + wp] = vA;
                out[(((size_t)b * COUT + co) * H + r1) * W + wp] = vB;
            }
        }
    }
}

extern "C" void kernel_launch(void* const* d_in, const int* in_sizes, int n_in,
                              void* d_out, int out_size, void* d_ws, size_t ws_size,
                              hipStream_t stream) {
    const float* x  = (const float*)d_in[0];
    const float* wo = (const float*)d_in[1];
    const float* bo = (const float*)d_in[2];
    const float* wc = (const float*)d_in[3];
    const float* bc = (const float*)d_in[4];
    float* out = (float*)d_out;

    _Float16* xt   = (_Float16*)d_ws;                                   // 16.78 MB
    _Float16* wao2 = (_Float16*)((char*)d_ws + (size_t)NB * H * W * CIN * 2);
    _Float16* wac2 = wao2 + 18432;

    int prep_blocks = NB * H + (18432 + 36864 + 255) / 256;             // 1024 + 216
    prep_fused<<<prep_blocks, 256, 0, stream>>>(x, xt, wo, wc, wao2, wac2);
    deform_fused<<<NB * H * W / (WR * WC), 256, 0, stream>>>(xt, wao2, wac2, bo, bc, out);
}